// Round 2
// baseline (479.037 us; speedup 1.0000x reference)
//
#include <hip/hip_runtime.h>
#include <hip/hip_fp16.h>
#include <stdint.h>

// Problem constants
#define NTOK 4096      // B*H*W tokens
#define CDIM 256
#define DDIM 2048
#define KCB  16384
#define CPAD 320       // 257 padded to 320 (bias at col 256)
#define MARGIN 0.03f   // screen-error margin in v-units (~100 sigma of f16 screen error)
#define CAP   64       // candidate slots per token

typedef _Float16 f16;
typedef _Float16 f16x8 __attribute__((ext_vector_type(8)));
typedef _Float16 f16x4 __attribute__((ext_vector_type(4)));
typedef float f32x4 __attribute__((ext_vector_type(4)));

typedef const __attribute__((address_space(1))) uint32_t* gptr_t;
typedef __attribute__((address_space(3))) uint32_t* lptr_t;
__device__ __forceinline__ void gload_lds16(const void* g, void* l) {
  __builtin_amdgcn_global_load_lds((gptr_t)g, (lptr_t)l, 16, 0, 0);
}

__device__ __forceinline__ unsigned encf(float f) {
  unsigned u = __float_as_uint(f);
  return (u & 0x80000000u) ? ~u : (u | 0x80000000u);
}
__device__ __forceinline__ float decf(unsigned e) {
  return (e & 0x80000000u) ? __uint_as_float(e ^ 0x80000000u) : __uint_as_float(~e);
}

// ---------------- init ----------------
__global__ void k_init(unsigned* smax, int* cnt) {
  int i = blockIdx.x * 256 + threadIdx.x;
  if (i < NTOK) { smax[i] = 0u; cnt[i] = 0; }
}

// ---------------- build W~^T (320 x 2048) f16 from qc_w (2048x256) + qc_b ----------------
__global__ __launch_bounds__(256) void k_build_wT(const float* qc_w, const float* qc_b, f16* wT) {
  __shared__ float tl[64][65];
  int d0 = blockIdx.x * 64, c0 = blockIdx.y * 64;
  int jj = threadIdx.x & 63, i0 = threadIdx.x >> 6;
  for (int ii = 0; ii < 64; ii += 4) {
    int i = ii + i0; int d = d0 + i; int c = c0 + jj;
    float v = 0.f;
    if (c < 256) v = qc_w[(size_t)d * 256 + c];
    else if (c == 256) v = qc_b[d];
    tl[i][jj] = v;
  }
  __syncthreads();
  for (int jj2 = 0; jj2 < 64; jj2 += 4) {
    int j = jj2 + i0; int i = threadIdx.x & 63;
    wT[(size_t)(c0 + j) * 2048 + d0 + i] = (f16)tl[i][j];
  }
}

// ---------------- build x tokens: x16 (4096x320 f16), x32 (4096x256 f32) ----------------
__global__ __launch_bounds__(256) void k_build_x(const float* hid, f16* x16, float* x32) {
  __shared__ float tl[64][65];
  int hw0 = blockIdx.x * 64, c0 = blockIdx.y * 64, b = blockIdx.z;
  int jj = threadIdx.x & 63, i0 = threadIdx.x >> 6;
  for (int ii = 0; ii < 64; ii += 4) {
    int i = ii + i0;
    tl[i][jj] = hid[((size_t)b * 256 + c0 + i) * 1024 + hw0 + jj];
  }
  __syncthreads();
  for (int jj2 = 0; jj2 < 64; jj2 += 4) {
    int j = jj2 + i0; int i = threadIdx.x & 63;
    int t = b * 1024 + hw0 + j; float v = tl[i][j];
    x32[(size_t)t * 256 + c0 + i] = v;
    x16[(size_t)t * 320 + c0 + i] = (f16)v;
  }
}
__global__ void k_pad_x(f16* x16) {
  int t = blockIdx.x; int p = threadIdx.x; // 64 threads
  x16[(size_t)t * 320 + 256 + p] = (p == 0) ? (f16)1.0f : (f16)0.0f;
}

// ---------------- codebook norms (f64) ----------------
__global__ __launch_bounds__(256) void k_cnorm(const float* cb, double* inv64, float* inv32) {
  int j = blockIdx.x; int tid = threadIdx.x;
  const float* row = cb + (size_t)j * 2048;
  f32x4 a = *(const f32x4*)(row + tid * 8);
  f32x4 b = *(const f32x4*)(row + tid * 8 + 4);
  double s = 0.0;
  for (int e = 0; e < 4; e++) { s += (double)a[e] * (double)a[e]; s += (double)b[e] * (double)b[e]; }
  for (int off = 32; off; off >>= 1) s += __shfl_down(s, off);
  __shared__ double wsum[4];
  int lane = tid & 63, w = tid >> 6;
  if (lane == 0) wsum[w] = s;
  __syncthreads();
  if (tid == 0) {
    double tot = wsum[0] + wsum[1] + wsum[2] + wsum[3];
    double n = sqrt(tot); n = fmax(n, 1e-12);
    double inv = 1.0 / n;
    inv64[j] = inv; inv32[j] = (float)inv;
  }
}

// ---------------- proj: h[t][d] = sum_c x[t][c]*qc_w[d][c] + qc_b[d], f64 accum ----------------
__global__ __launch_bounds__(256) void k_proj(const float* x32, const float* qc_w, const float* qc_b, double* h64) {
  __shared__ float At[64][68];
  __shared__ float Bt[64][68];
  int t0 = blockIdx.y * 64, d0 = blockIdx.x * 64;
  int tid = threadIdx.x;
  int rr = tid >> 4, cc = tid & 15;
  int lrow = tid >> 2, lseg = tid & 3;
  double acc[4][4] = {};
  for (int k0 = 0; k0 < 256; k0 += 64) {
    for (int i = 0; i < 4; i++) {
      int kk = lseg * 16 + 4 * i;
      f32x4 va = *(const f32x4*)(x32 + (size_t)(t0 + lrow) * 256 + k0 + kk);
      f32x4 vb = *(const f32x4*)(qc_w + (size_t)(d0 + lrow) * 256 + k0 + kk);
      for (int e = 0; e < 4; e++) { At[kk + e][lrow] = va[e]; Bt[kk + e][lrow] = vb[e]; }
    }
    __syncthreads();
    for (int k = 0; k < 64; k++) {
      f32x4 a = *(const f32x4*)&At[k][rr * 4];
      f32x4 b = *(const f32x4*)&Bt[k][cc * 4];
#pragma unroll
      for (int i = 0; i < 4; i++)
#pragma unroll
        for (int j = 0; j < 4; j++)
          acc[i][j] += (double)a[i] * (double)b[j];
    }
    __syncthreads();
  }
  for (int i = 0; i < 4; i++)
    for (int j = 0; j < 4; j++) {
      int col = d0 + cc * 4 + j;
      h64[(size_t)(t0 + rr * 4 + i) * 2048 + col] = acc[i][j] + (double)qc_b[col];
    }
}

// ---------------- P' GEMM: P16[j][c] = sum_d cb[j][d]*wT[c][d]  (16384x320), f16 out ----------------
__global__ __launch_bounds__(256) void k_pgemm(const float* cb, const f16* wT, f16* P16) {
  __shared__ f16 Al[2][128][32];
  __shared__ f16 Bl[2][160][32];
  int j0 = blockIdx.x * 128;
  int c0 = blockIdx.y * 160;
  int tid = threadIdx.x, wid = tid >> 6, lane = tid & 63;
  f32x4 acc[2][10];
  for (int m = 0; m < 2; m++) for (int n = 0; n < 10; n++) acc[m][n] = (f32x4)0.0f;
  int arow = tid >> 1, aseg = tid & 1;

  auto stageA = [&](int kk, int buf) {
    for (int i = 0; i < 4; i++) {
      f32x4 v = *(const f32x4*)(cb + (size_t)(j0 + arow) * 2048 + kk + aseg * 16 + 4 * i);
      f16x4 h; h[0] = (f16)v[0]; h[1] = (f16)v[1]; h[2] = (f16)v[2]; h[3] = (f16)v[3];
      *(f16x4*)&Al[buf][arow][aseg * 16 + 4 * i] = h;
    }
  };
  auto stageB = [&](int kk, int buf) {
    for (int r16 = wid; r16 < 10; r16 += 4) {
      int row = r16 * 16 + (lane >> 2);
      gload_lds16(wT + (size_t)(c0 + row) * 2048 + kk + (lane & 3) * 8, &Bl[buf][r16 * 16][0]);
    }
  };
  stageA(0, 0); stageB(0, 0);
  asm volatile("s_waitcnt vmcnt(0)" ::: "memory");
  __syncthreads();
  for (int s = 0; s < 64; s++) {
    int buf = s & 1;
    if (s + 1 < 64) { stageA((s + 1) * 32, buf ^ 1); stageB((s + 1) * 32, buf ^ 1); }
    int kb = (lane >> 4) * 8, cl = lane & 15;
    f16x8 av0 = *(const f16x8*)&Al[buf][32 * wid + cl][kb];
    f16x8 av1 = *(const f16x8*)&Al[buf][32 * wid + 16 + cl][kb];
#pragma unroll
    for (int n = 0; n < 10; n++) {
      f16x8 bv = *(const f16x8*)&Bl[buf][16 * n + cl][kb];
      acc[0][n] = __builtin_amdgcn_mfma_f32_16x16x32_f16(av0, bv, acc[0][n], 0, 0, 0);
      acc[1][n] = __builtin_amdgcn_mfma_f32_16x16x32_f16(av1, bv, acc[1][n], 0, 0, 0);
    }
    asm volatile("s_waitcnt vmcnt(0)" ::: "memory");
    __syncthreads();
  }
  int g = lane >> 4, cl = lane & 15;
  for (int m = 0; m < 2; m++)
    for (int n = 0; n < 10; n++)
      for (int r = 0; r < 4; r++) {
        int row = j0 + 32 * wid + 16 * m + 4 * g + r;
        int col = c0 + 16 * n + cl;
        P16[(size_t)row * 320 + col] = (f16)acc[m][n][r];
      }
}

// ---------------- screen GEMM: sim[t][j] = (x16[t] . P16[j]) * inv32[j] ----------------
// PASS 0: per-token max -> smax (atomic).  PASS 1: collect candidates >= max - MARGIN.
template <int PASS>
__global__ __launch_bounds__(256) void k_screen(const f16* x16, const f16* P16, const float* inv32,
                                                unsigned* smax, int* cnt, int* cand) {
  __shared__ f16 Al[2][128][32];
  __shared__ f16 Bl[2][128][32];
  int t0 = blockIdx.y * 128, n0 = blockIdx.x * 128;
  int tid = threadIdx.x, wid = tid >> 6, lane = tid & 63;
  int wr = wid >> 1, wc = wid & 1;
  f32x4 acc[4][4];
  for (int m = 0; m < 4; m++) for (int n = 0; n < 4; n++) acc[m][n] = (f32x4)0.0f;

  auto stage = [&](int kk, int buf) {
    for (int i = 0; i < 2; i++) {
      int row = 32 * wid + 16 * i + (lane >> 2);
      gload_lds16(x16 + (size_t)(t0 + row) * 320 + kk + (lane & 3) * 8, &Al[buf][32 * wid + 16 * i][0]);
      gload_lds16(P16 + (size_t)(n0 + row) * 320 + kk + (lane & 3) * 8, &Bl[buf][32 * wid + 16 * i][0]);
    }
  };
  stage(0, 0);
  asm volatile("s_waitcnt vmcnt(0)" ::: "memory");
  __syncthreads();
  for (int s = 0; s < 10; s++) {
    int buf = s & 1;
    if (s + 1 < 10) stage((s + 1) * 32, buf ^ 1);
    int kb = (lane >> 4) * 8, cl = lane & 15;
    f16x8 av[4], bv[4];
#pragma unroll
    for (int m = 0; m < 4; m++) av[m] = *(const f16x8*)&Al[buf][64 * wr + 16 * m + cl][kb];
#pragma unroll
    for (int n = 0; n < 4; n++) bv[n] = *(const f16x8*)&Bl[buf][64 * wc + 16 * n + cl][kb];
#pragma unroll
    for (int m = 0; m < 4; m++)
#pragma unroll
      for (int n = 0; n < 4; n++)
        acc[m][n] = __builtin_amdgcn_mfma_f32_16x16x32_f16(av[m], bv[n], acc[m][n], 0, 0, 0);
    asm volatile("s_waitcnt vmcnt(0)" ::: "memory");
    __syncthreads();
  }
  int g = lane >> 4, cl = lane & 15;
  float invv[4];
#pragma unroll
  for (int n = 0; n < 4; n++) invv[n] = inv32[n0 + 64 * wc + 16 * n + cl];
  if (PASS == 0) {
#pragma unroll
    for (int m = 0; m < 4; m++) {
#pragma unroll
      for (int r = 0; r < 4; r++) {
        float v = -3.4e38f;
#pragma unroll
        for (int n = 0; n < 4; n++) v = fmaxf(v, acc[m][n][r] * invv[n]);
        v = fmaxf(v, __shfl_xor(v, 1));
        v = fmaxf(v, __shfl_xor(v, 2));
        v = fmaxf(v, __shfl_xor(v, 4));
        v = fmaxf(v, __shfl_xor(v, 8));
        if (cl == 0) {
          int row = t0 + 64 * wr + 16 * m + 4 * g + r;
          atomicMax(&smax[row], encf(v));
        }
      }
    }
  } else {
#pragma unroll
    for (int m = 0; m < 4; m++) {
#pragma unroll
      for (int r = 0; r < 4; r++) {
        int row = t0 + 64 * wr + 16 * m + 4 * g + r;
        float lim = decf(smax[row]) - MARGIN;
#pragma unroll
        for (int n = 0; n < 4; n++) {
          float v = acc[m][n][r] * invv[n];
          if (v >= lim) {
            int slot = atomicAdd(&cnt[row], 1);
            if (slot < CAP) cand[row * CAP + slot] = n0 + 64 * wc + 16 * n + cl;
          }
        }
      }
    }
  }
}

// ---------------- rescore candidates in f64, pick argmax (tie: lowest idx) ----------------
__global__ __launch_bounds__(256) void k_rescore(const double* h64, const float* cb, const double* inv64,
                                                 const int* cnt, const int* cand, float* idxf, int* idxi) {
  __shared__ double hsh[2048];
  __shared__ double red[256];
  __shared__ int    redi[256];
  int t = blockIdx.x, tid = threadIdx.x;
  for (int i = 0; i < 8; i++) hsh[tid + 256 * i] = h64[(size_t)t * 2048 + tid + 256 * i];
  __syncthreads();
  int n = cnt[t];
  double bV = -1e300; int bI = 0x7fffffff;
  if (n <= CAP) {
    for (int c = 0; c < n; c++) {
      int code = cand[t * CAP + c];
      const float* row = cb + (size_t)code * 2048;
      double p = 0.0;
      for (int i = 0; i < 8; i++) { int d = tid + 256 * i; p += hsh[d] * (double)row[d]; }
      red[tid] = p; __syncthreads();
      for (int s2 = 128; s2; s2 >>= 1) { if (tid < s2) red[tid] += red[tid + s2]; __syncthreads(); }
      if (tid == 0) {
        double sv = red[0] * inv64[code];
        if (sv > bV || (sv == bV && code < bI)) { bV = sv; bI = code; }
      }
      __syncthreads();
    }
  } else {
    // overflow fallback: exact full scan over all codes (should never trigger)
    for (int code = tid; code < KCB; code += 256) {
      const float* row = cb + (size_t)code * 2048;
      double p = 0.0;
      for (int d = 0; d < 2048; d++) p += hsh[d] * (double)row[d];
      double sv = p * inv64[code];
      if (sv > bV || (sv == bV && code < bI)) { bV = sv; bI = code; }
    }
    red[tid] = bV; redi[tid] = bI; __syncthreads();
    for (int s2 = 128; s2; s2 >>= 1) {
      if (tid < s2) {
        double ov = red[tid + s2]; int oi = redi[tid + s2];
        if (ov > red[tid] || (ov == red[tid] && oi < redi[tid])) { red[tid] = ov; redi[tid] = oi; }
      }
      __syncthreads();
    }
    if (tid == 0) { bV = red[0]; bI = redi[0]; }
  }
  if (tid == 0) { idxi[t] = bI; idxf[t] = (float)bI; }
}

// ---------------- gather quant output: out[b][d][hw] = cb[idx[t]][d] * inv32[idx[t]] ----------------
__global__ __launch_bounds__(256) void k_quant(const float* cb, const float* inv32, const int* idxi, float* out0) {
  int hw = blockIdx.x * 256 + threadIdx.x;
  int d = blockIdx.y, b = blockIdx.z;
  int t = b * 1024 + hw;
  int row = idxi[t];
  out0[((size_t)b * 2048 + d) * 1024 + hw] = cb[(size_t)row * 2048 + d] * inv32[row];
}

extern "C" void kernel_launch(void* const* d_in, const int* in_sizes, int n_in,
                              void* d_out, int out_size, void* d_ws, size_t ws_size,
                              hipStream_t stream) {
  const float* hid = (const float*)d_in[0];
  const float* cb  = (const float*)d_in[1];
  const float* qw  = (const float*)d_in[2];
  const float* qb  = (const float*)d_in[3];
  float* out = (float*)d_out;  // [4*2048*1024 quant][4096 idx-as-float]

  char* w = (char*)d_ws;
  size_t off = 0;
  auto alloc = [&](size_t bytes) -> void* {
    void* p = w + off;
    off += (bytes + 255) & ~(size_t)255;
    return p;
  };
  double* h64  = (double*)alloc((size_t)NTOK * 2048 * 8);
  f16*    x16  = (f16*)   alloc((size_t)NTOK * 320 * 2);
  float*  x32  = (float*) alloc((size_t)NTOK * 256 * 4);
  f16*    wT   = (f16*)   alloc((size_t)320 * 2048 * 2);
  f16*    P16  = (f16*)   alloc((size_t)KCB * 320 * 2);
  double* inv64= (double*)alloc((size_t)KCB * 8);
  float*  inv32= (float*) alloc((size_t)KCB * 4);
  unsigned* smax=(unsigned*)alloc((size_t)NTOK * 4);
  int*    cnt  = (int*)   alloc((size_t)NTOK * 4);
  int*    cand = (int*)   alloc((size_t)NTOK * CAP * 4);
  int*    idxi = (int*)   alloc((size_t)NTOK * 4);

  k_init<<<16, 256, 0, stream>>>(smax, cnt);
  k_build_wT<<<dim3(32, 5), 256, 0, stream>>>(qw, qb, wT);
  k_build_x<<<dim3(16, 4, 4), 256, 0, stream>>>(hid, x16, x32);
  k_pad_x<<<NTOK, 64, 0, stream>>>(x16);
  k_cnorm<<<KCB, 256, 0, stream>>>(cb, inv64, inv32);
  k_proj<<<dim3(32, 64), 256, 0, stream>>>(x32, qw, qb, h64);
  k_pgemm<<<dim3(128, 2), 256, 0, stream>>>(cb, wT, P16);
  k_screen<0><<<dim3(128, 32), 256, 0, stream>>>(x16, P16, inv32, smax, cnt, cand);
  k_screen<1><<<dim3(128, 32), 256, 0, stream>>>(x16, P16, inv32, smax, cnt, cand);
  k_rescore<<<NTOK, 256, 0, stream>>>(h64, cb, inv64, cnt, cand, out + 8388608, idxi);
  k_quant<<<dim3(4, 2048, 4), 256, 0, stream>>>(cb, inv32, idxi, out);
}